// Round 4
// baseline (2727.844 us; speedup 1.0000x reference)
//
#include <hip/hip_runtime.h>
#include <hip/hip_bf16.h>
#include <stdint.h>

typedef unsigned short ushort_t;

#define HID 512
#define FOURH 2048
#define BSZ 32
#define SLEN 50
#define TDEC 39
#define EMB 256
#define VOC 32000

using short8  = __attribute__((ext_vector_type(8))) short;
using float4v = __attribute__((ext_vector_type(4))) float;

__device__ inline float bf16lo(uint32_t u) { return __uint_as_float(u << 16); }
__device__ inline float bf16hi(uint32_t u) { return __uint_as_float(u & 0xffff0000u); }

__device__ inline ushort_t f32_to_bf16(float f) {
    uint32_t u = __float_as_uint(f);
    uint32_t r = (u + 0x7fffu + ((u >> 16) & 1u)) >> 16;
    return (ushort_t)r;
}

__device__ inline float sigmoid_f(float x) { return 1.0f / (1.0f + expf(-x)); }

// ---------------------------------------------------------------------------
// Runtime dtype detection. Probe = enc_b0 (values ~N(0,1)*0.05).
// If the input tensors are bf16: every u16 is a bf16 with |x| < 0.5 ->
// exponent < 0x8A always. If they are fp32: even-indexed u16s are raw
// mantissa bits (uniform), so among 64 u16s ~32 are uniform -> P(all
// exponents < 0x8A) ~ 6e-19. Returns 1 if inputs are fp32.
// Wave-uniform result (all threads compute the same value).
// ---------------------------------------------------------------------------
__device__ inline int detect_f32(const ushort_t* __restrict__ probe) {
    int cnt = 0;
#pragma unroll
    for (int i = 0; i < 64; ++i) {
        int e = (probe[i] >> 7) & 0xFF;
        cnt += (e >= 0x8A);
    }
    return cnt > 0;
}

// ---------------------------------------------------------------------------
// Embedding gather -> bf16 pairs. Handles bf16 or fp32 source table.
// out[i] packs elements (2c, 2c+1) of row idx[tok].
// ---------------------------------------------------------------------------
__global__ void embed_kernel(const int* __restrict__ idx,
                             const void* __restrict__ emb,
                             uint32_t* __restrict__ out,
                             int total_u,
                             const ushort_t* __restrict__ probe)
{
    const int F32 = detect_f32(probe);
    int i = blockIdx.x * 256 + threadIdx.x;
    if (i >= total_u) return;
    int tok = i >> 7;          // EMB/2 = 128 uints per row
    int col = i & 127;
    int row = idx[tok];
    if (F32) {
        const float* ef = (const float*)emb + (size_t)row * EMB + col * 2;
        uint32_t lo = f32_to_bf16(ef[0]);
        uint32_t hi = f32_to_bf16(ef[1]);
        out[i] = lo | (hi << 16);
    } else {
        out[i] = ((const uint32_t*)emb)[(size_t)row * 128 + col];
    }
}

// ---------------------------------------------------------------------------
// Load an 8-element bf16 fragment from W (which may be bf16 or fp32 storage).
// ---------------------------------------------------------------------------
__device__ inline short8 load_w_frag(const void* __restrict__ W, size_t elem_off, int F32) {
    if (F32) {
        const float* p = (const float*)W + elem_off;
        short8 r;
#pragma unroll
        for (int j = 0; j < 8; ++j) r[j] = (short)f32_to_bf16(p[j]);
        return r;
    }
    return *(const short8*)((const ushort_t*)W + elem_off);
}

__device__ inline float load_bias(const void* __restrict__ bias, int n, int F32) {
    if (F32) return ((const float*)bias)[n];
    return __uint_as_float(((uint32_t)((const ushort_t*)bias)[n]) << 16);
}

// ---------------------------------------------------------------------------
// GEMM: C[M,N] = A[M,K](bf16, internal) @ W[N,K](bf16|fp32)^T + bias
// MFMA 16x16x32 bf16, 64x64 block tile, 4 waves.
// SMODE 0: C = float* scratch, C[m*N+n] = v          (gate pre-activations)
// SMODE 1: C = d_out base; element idx = (32+m)*N+n; store fp32 or bf16
//          per detected mode                          (final logits)
// ---------------------------------------------------------------------------
template <int SMODE>
__global__ void gemm_bias_kernel(const ushort_t* __restrict__ A,
                                 const void* __restrict__ W,
                                 const void* __restrict__ bias,
                                 void* __restrict__ C,
                                 int M, int N, int K,
                                 const ushort_t* __restrict__ probe)
{
    const int F32 = detect_f32(probe);
    const int lane = threadIdx.x & 63;
    const int wave = threadIdx.x >> 6;
    const int quad = lane >> 4;
    const int l16  = lane & 15;

    const int m_base = blockIdx.y * 64 + wave * 16;
    if (m_base >= M) return;               // M is a multiple of 16
    const int n_base = blockIdx.x * 64;
    const int m_row  = m_base + l16;

    const ushort_t* Arow = A + (size_t)m_row * K + quad * 8;

    float4v acc[4];
#pragma unroll
    for (int nt = 0; nt < 4; ++nt) acc[nt] = (float4v){0.f, 0.f, 0.f, 0.f};

    for (int k0 = 0; k0 < K; k0 += 32) {
        short8 a = *(const short8*)(Arow + k0);
#pragma unroll
        for (int nt = 0; nt < 4; ++nt) {
            size_t woff = (size_t)(n_base + nt * 16 + l16) * K + k0 + quad * 8;
            short8 b = load_w_frag(W, woff, F32);
            acc[nt] = __builtin_amdgcn_mfma_f32_16x16x32_bf16(a, b, acc[nt], 0, 0, 0);
        }
    }

#pragma unroll
    for (int nt = 0; nt < 4; ++nt) {
        int n = n_base + nt * 16 + l16;
        float bv = load_bias(bias, n, F32);
#pragma unroll
        for (int r = 0; r < 4; ++r) {
            int m = m_base + quad * 4 + r;
            float v = acc[nt][r] + bv;
            if (SMODE == 0) {
                ((float*)C)[(size_t)m * N + n] = v;
            } else {
                size_t idx = (size_t)(BSZ + m) * N + n;   // skip zero timestep
                if (F32) ((float*)C)[idx] = v;
                else     ((ushort_t*)C)[idx] = f32_to_bf16(v);
            }
        }
    }
}

// ---------------------------------------------------------------------------
// One LSTM timestep: g = xih(fp32, precomputed) + h_in @ Whh^T ; cell update.
// 256 blocks x 256 threads; block owns 2 hidden units x 32 batch x 4 gates.
// Whh may be bf16 or fp32 storage; h/c are internal (bf16 / fp32).
// ---------------------------------------------------------------------------
__global__ void lstm_step_kernel(const float* __restrict__ xih,     // (32,2048) this t
                                 const ushort_t* __restrict__ h_in, // (32,512) bf16
                                 ushort_t* __restrict__ h_out,      // (32,512) bf16
                                 float* __restrict__ c,             // (32,512) fp32
                                 const void* __restrict__ Whh,      // (2048,512)
                                 ushort_t* __restrict__ ys,         // (32,512) or null
                                 const ushort_t* __restrict__ probe)
{
    const int F32 = detect_f32(probe);
    __shared__ uint32_t h_lds[BSZ * 257];   // padded rows
    __shared__ uint32_t w_lds[8 * 256];
    __shared__ float    g_lds[8][BSZ];

    const int tid = threadIdx.x;
    const int j0  = blockIdx.x * 2;

    const uint32_t* h32 = (const uint32_t*)h_in;
#pragma unroll
    for (int i = 0; i < 32; ++i) {                 // 8192 uints
        int idx = tid + i * 256;
        int row = idx >> 8, col = idx & 255;
        h_lds[row * 257 + col] = h32[idx];
    }

#pragma unroll
    for (int i = 0; i < 8; ++i) {                  // 2048 uints (8 Whh rows)
        int idx  = tid + i * 256;
        int lrr  = idx >> 8, col = idx & 255;
        int gate = lrr >> 1, jl = lrr & 1;
        size_t wrow = (size_t)(gate * HID + j0 + jl);
        if (F32) {
            const float* wf = (const float*)Whh + wrow * HID + col * 2;
            uint32_t lo = f32_to_bf16(wf[0]);
            uint32_t hi = f32_to_bf16(wf[1]);
            w_lds[lrr * 256 + col] = lo | (hi << 16);
        } else {
            w_lds[lrr * 256 + col] = ((const uint32_t*)Whh)[wrow * 256 + col];
        }
    }
    __syncthreads();

    const int b    = tid & 31;
    const int lr   = tid >> 5;          // (gate<<1)|jl
    const int gate = lr >> 1;
    const int jl   = lr & 1;

    float dot = xih[b * FOURH + gate * HID + j0 + jl];
    const uint32_t* hr = &h_lds[b * 257];
    const uint32_t* wr = &w_lds[lr * 256];
    float s0 = 0.f, s1 = 0.f;
#pragma unroll 8
    for (int k = 0; k < 256; ++k) {
        uint32_t hu = hr[k], wu = wr[k];
        s0 += bf16lo(hu) * bf16lo(wu);
        s1 += bf16hi(hu) * bf16hi(wu);
    }
    g_lds[lr][b] = dot + s0 + s1;
    __syncthreads();

    if (tid < 64) {
        int b2 = tid & 31, jl2 = tid >> 5;
        int j  = j0 + jl2;
        float gi = g_lds[(0 << 1) | jl2][b2];
        float gf = g_lds[(1 << 1) | jl2][b2];
        float gg = g_lds[(2 << 1) | jl2][b2];
        float go = g_lds[(3 << 1) | jl2][b2];
        float cold = c[b2 * HID + j];
        float cn = sigmoid_f(gf) * cold + sigmoid_f(gi) * tanhf(gg);
        float hn = sigmoid_f(go) * tanhf(cn);
        c[b2 * HID + j] = cn;
        ushort_t hb = f32_to_bf16(hn);
        h_out[b2 * HID + j] = hb;
        if (ys) ys[b2 * HID + j] = hb;
    }
}

// ---------------------------------------------------------------------------
// Zero the first output timestep (elements [0, 32*VOC)), dtype per mode.
// ---------------------------------------------------------------------------
__global__ void zero_row_kernel(void* __restrict__ outv,
                                const ushort_t* __restrict__ probe)
{
    const int F32 = detect_f32(probe);
    int i = blockIdx.x * 256 + threadIdx.x;
    if (i >= BSZ * VOC) return;
    if (F32) ((uint32_t*)outv)[i] = 0u;
    else     ((ushort_t*)outv)[i] = 0;
}

// ---------------------------------------------------------------------------
// All scratch lives inside d_out:
//   elems [0, 32*VOC)  = first-timestep zero region (written LAST);
//   dy1 (bf16, 1.28 MB) at byte 0 — projection writes start at byte
//     32*VOC*esize >= 2.048 MB, so dy1 survives until the projection reads it;
//   arena at byte 4 MiB (> 32*VOC*4) for all other intermediates — all dead
//     before the projection overwrites that region with logits.
// ---------------------------------------------------------------------------
extern "C" void kernel_launch(void* const* d_in, const int* in_sizes, int n_in,
                              void* d_out, int out_size, void* d_ws, size_t ws_size,
                              hipStream_t stream)
{
    const int*      src      = (const int*)d_in[0];
    const int*      trg      = (const int*)d_in[1];
    const void*     enc_emb  = d_in[2];
    const void*     enc_Wih0 = d_in[3];
    const void*     enc_Whh0 = d_in[4];
    const void*     enc_b0   = d_in[5];
    const void*     enc_Wih1 = d_in[6];
    const void*     enc_Whh1 = d_in[7];
    const void*     enc_b1   = d_in[8];
    const void*     dec_emb  = d_in[9];
    const void*     dec_Wih0 = d_in[10];
    const void*     dec_Whh0 = d_in[11];
    const void*     dec_b0   = d_in[12];
    const void*     dec_Wih1 = d_in[13];
    const void*     dec_Whh1 = d_in[14];
    const void*     dec_b1   = d_in[15];
    const void*     out_W    = d_in[16];
    const void*     out_b    = d_in[17];

    const ushort_t* probe = (const ushort_t*)enc_b0;   // dtype probe

    const int ME = SLEN * BSZ;   // 1600
    const int MD = TDEC * BSZ;   // 1248

    // dy1 (internal bf16) at d_out byte 0: MD*HID*2 = 1,277,952 B, safely below
    // the earliest projection write (byte 32*VOC*2 = 2,048,000 in bf16 mode).
    ushort_t* dy1 = (ushort_t*)d_out;

    // Arena beyond the fp32-mode zero region (32*VOC*4 = 4,096,000 B).
    char*  arena = (char*)d_out + (4u << 20);          // 4 MiB
    size_t aoff  = 0;
    auto acarve = [&](size_t bytes) -> void* {
        void* p = arena + aoff;
        aoff = (aoff + bytes + 255) & ~(size_t)255;
        return p;
    };
    const size_t HSTATE = (size_t)BSZ * HID;                       // 16384 elems
    float*    Xbig = (float*)acarve((size_t)ME * FOURH * 4);       // 13.1 MB fp32
    ushort_t* X0   = (ushort_t*)acarve((size_t)ME * EMB * 2);
    ushort_t* DX0  = (ushort_t*)acarve((size_t)MD * EMB * 2);
    ushort_t* ys0  = (ushort_t*)acarve((size_t)ME * HID * 2);
    ushort_t* dy0  = (ushort_t*)acarve((size_t)MD * HID * 2);
    ushort_t* h0b  = (ushort_t*)acarve(2 * HSTATE * 2);            // dbl-buffered h
    float*    c0b  = (float*)acarve(HSTATE * 4);
    ushort_t* h1b  = (ushort_t*)acarve(2 * HSTATE * 2);
    float*    c1b  = (float*)acarve(HSTATE * 4);
    // arena end ~ 4 MiB + 17.8 MB ~ 22 MB << 81.9 MB (bf16 out) or 163.8 MB (fp32)

    // init recurrent states (parity-0 h buffers + cells)
    hipMemsetAsync(h0b, 0, HSTATE * 2, stream);
    hipMemsetAsync(c0b, 0, HSTATE * 4, stream);
    hipMemsetAsync(h1b, 0, HSTATE * 2, stream);
    hipMemsetAsync(c1b, 0, HSTATE * 4, stream);

    // embeddings
    {
        int tu = ME * (EMB / 2);
        embed_kernel<<<(tu + 255) / 256, 256, 0, stream>>>(
            src, enc_emb, (uint32_t*)X0, tu, probe);
        int td = MD * (EMB / 2);
        embed_kernel<<<(td + 255) / 256, 256, 0, stream>>>(
            trg, dec_emb, (uint32_t*)DX0, td, probe);
    }

    const size_t XIH_T = (size_t)BSZ * FOURH;

    // encoder layer 0
    gemm_bias_kernel<0><<<dim3(FOURH / 64, (ME + 63) / 64), 256, 0, stream>>>(
        X0, enc_Wih0, enc_b0, Xbig, ME, FOURH, EMB, probe);
    for (int t = 0; t < SLEN; ++t) {
        lstm_step_kernel<<<256, 256, 0, stream>>>(
            Xbig + (size_t)t * XIH_T,
            h0b + (t & 1) * HSTATE, h0b + ((t + 1) & 1) * HSTATE,
            c0b, enc_Whh0, ys0 + (size_t)t * HSTATE, probe);
    }
    // encoder layer 1 (only final state needed)
    gemm_bias_kernel<0><<<dim3(FOURH / 64, (ME + 63) / 64), 256, 0, stream>>>(
        ys0, enc_Wih1, enc_b1, Xbig, ME, FOURH, HID, probe);
    for (int t = 0; t < SLEN; ++t) {
        lstm_step_kernel<<<256, 256, 0, stream>>>(
            Xbig + (size_t)t * XIH_T,
            h1b + (t & 1) * HSTATE, h1b + ((t + 1) & 1) * HSTATE,
            c1b, enc_Whh1, (ushort_t*)nullptr, probe);
    }
    // 50 steps (even): final h at parity 0 -> decoder t=0 reads parity 0.

    // decoder layer 0 (continues h0b/c0b)
    gemm_bias_kernel<0><<<dim3(FOURH / 64, (MD + 63) / 64), 256, 0, stream>>>(
        DX0, dec_Wih0, dec_b0, Xbig, MD, FOURH, EMB, probe);
    for (int t = 0; t < TDEC; ++t) {
        lstm_step_kernel<<<256, 256, 0, stream>>>(
            Xbig + (size_t)t * XIH_T,
            h0b + (t & 1) * HSTATE, h0b + ((t + 1) & 1) * HSTATE,
            c0b, dec_Whh0, dy0 + (size_t)t * HSTATE, probe);
    }
    // decoder layer 1 (continues h1b/c1b)
    gemm_bias_kernel<0><<<dim3(FOURH / 64, (MD + 63) / 64), 256, 0, stream>>>(
        dy0, dec_Wih1, dec_b1, Xbig, MD, FOURH, HID, probe);
    for (int t = 0; t < TDEC; ++t) {
        lstm_step_kernel<<<256, 256, 0, stream>>>(
            Xbig + (size_t)t * XIH_T,
            h1b + (t & 1) * HSTATE, h1b + ((t + 1) & 1) * HSTATE,
            c1b, dec_Whh1, dy1 + (size_t)t * HSTATE, probe);
    }

    // projection: reads dy1 (bytes [0,1.28MB)) + out_W/out_b (inputs);
    // writes elements [(32)*VOC, 1280*VOC) of d_out. Arena is dead.
    gemm_bias_kernel<1><<<dim3(VOC / 64, (MD + 63) / 64), 256, 0, stream>>>(
        dy1, out_W, out_b, d_out, MD, VOC, HID, probe);

    // zero first output timestep (elements [0, 32*VOC)) — also wipes dy1.
    zero_row_kernel<<<(BSZ * VOC + 255) / 256, 256, 0, stream>>>(d_out, probe);
}